// Round 5
// baseline (2165.700 us; speedup 1.0000x reference)
//
#include <hip/hip_runtime.h>
#include <math.h>

#define HIDDEN 4096
#define NEXP   128
#define TOPK   8
#define BM     32     // tokens per block
#define BK     64     // K chunk (= 32 k-pairs)
#define SS     132    // padded stride for epilogue score rows

// ---------------------------------------------------------------------------
// Pre-kernel: build wT2[k2][e][j] = w[e][2*k2+j]  (k-pair-interleaved
// transpose, 2 MB into d_ws). Router staging then copies contiguous 32 KB
// chunks, and each lane's B read is a contiguous ds_read_b64 giving its
// expert's two consecutive k values.
// ---------------------------------------------------------------------------
__global__ __launch_bounds__(256) void transpose_w(
    const float* __restrict__ w, float* __restrict__ wT2)
{
    const int t  = blockIdx.x * 256 + threadIdx.x;  // 0..262143
    const int e  = t & 127;
    const int k2 = t >> 7;                          // 0..2047
    const float2 v = *(const float2*)(w + (size_t)e * HIDDEN + 2 * k2);
    *(float2*)(wT2 + (size_t)k2 * 256 + 2 * e) = v; // lanes contiguous
}

// ---------------------------------------------------------------------------
// Router. Exactness contract: every (token,expert) logit is ONE fp32
// accumulator updated by fmaf with k strictly ascending 0..4095 — the same
// chain realization as the passing rounds 1/4 (matches the np/BLAS ref).
// Wave layout: wv>>1 = token half (16 wave-uniform tokens -> A via s_load),
// wv&1 = expert half, lane = expert within half. acc[16] VGPRs per lane.
// Grid T/32 = 512 blocks, 256 threads, 2 blocks/CU (8 waves/CU).
// ---------------------------------------------------------------------------
__global__ __launch_bounds__(256, 2) void router_kernel(
    const float* __restrict__ h,     // [T, HIDDEN]
    const float* __restrict__ wT2,   // k-pair-interleaved transposed w
    const float* __restrict__ bias,  // [NEXP]
    float* __restrict__ out,         // [T*8] indices (as float) ++ [T*8] weights
    int T)
{
    __shared__ float smem[2 * BK / 2 * 256];  // 2 x 8192 floats = 64 KB
    const int tid  = threadIdx.x;
    const int lane = tid & 63;
    const int wv   = __builtin_amdgcn_readfirstlane(tid >> 6);
    const int row0 = blockIdx.x * BM;
    const int eIdx = 64 * (wv & 1) + lane;          // this lane's expert

    // wave-uniform A base: tokens row0 + 16*(wv>>1) + tl, tl = 0..15
    const float* hbase = h + (size_t)(row0 + 16 * (wv >> 1)) * HIDDEN;

    float acc[16];
#pragma unroll
    for (int i = 0; i < 16; ++i) acc[i] = 0.0f;

    // ---- prefetch B chunk 0 (32 KB contiguous) into registers
    float4 pb[8];
#pragma unroll
    for (int i = 0; i < 8; ++i)
        pb[i] = *(const float4*)(wT2 + i * 1024 + tid * 4);

    for (int c = 0; c < HIDDEN / BK; ++c) {
        float* buf = smem + (c & 1) * 8192;
        // ---- store prefetched B chunk: contiguous b128, conflict-free
#pragma unroll
        for (int i = 0; i < 8; ++i)
            *(float4*)(buf + i * 1024 + tid * 4) = pb[i];
        __syncthreads();   // stores visible; prior buf's readers already done

        // ---- prefetch next chunk (in flight during compute)
        if (c + 1 < HIDDEN / BK) {
#pragma unroll
            for (int i = 0; i < 8; ++i)
                pb[i] = *(const float4*)(wT2 + (size_t)(c + 1) * 8192 + i * 1024 + tid * 4);
        }

        // ---- compute: 16 groups of 4 k. A via wave-uniform s_load, B via b64.
        const int k0 = c * BK;
#pragma unroll 4
        for (int g = 0; g < 16; ++g) {
            const float2 b0 = *(const float2*)(buf + (2 * g + 0) * 256 + 2 * eIdx);
            const float2 b1 = *(const float2*)(buf + (2 * g + 1) * 256 + 2 * eIdx);
            float4 av[16];
#pragma unroll
            for (int tl = 0; tl < 16; ++tl)
                av[tl] = *(const float4*)(hbase + (size_t)tl * HIDDEN + k0 + 4 * g);
#pragma unroll
            for (int tl = 0; tl < 16; ++tl) {
                acc[tl] = fmaf(av[tl].x, b0.x, acc[tl]);  // k = k0+4g
                acc[tl] = fmaf(av[tl].y, b0.y, acc[tl]);  // k+1
                acc[tl] = fmaf(av[tl].z, b1.x, acc[tl]);  // k+2
                acc[tl] = fmaf(av[tl].w, b1.y, acc[tl]);  // k+3
            }
        }
    }

    // ---- logits -> shared score buffer Ss[token][expert]
    __syncthreads();
    float* Ss = smem;
#pragma unroll
    for (int tl = 0; tl < 16; ++tl)
        Ss[(16 * (wv >> 1) + tl) * SS + eIdx] = acc[tl];
    __syncthreads();

    // ---- top-8 epilogue: verbatim round-1 (passed) logic, BM=32
    const float bb0 = bias[lane];
    const float bb1 = bias[lane + 64];

    for (int t = wv; t < BM; t += 4) {
        const float lg0 = Ss[t * SS + lane];
        const float lg1 = Ss[t * SS + 64 + lane];
        const float s0 = 1.0f / (1.0f + expf(-lg0));  // raw sigmoid score
        const float s1 = 1.0f / (1.0f + expf(-lg1));
        float c0 = s0 + bb0;                          // bias-corrected (selection)
        float c1 = s1 + bb1;

        int   sel_i[TOPK];
        float sel_r[TOPK];
        float rsum = 0.0f;
#pragma unroll
        for (int j = 0; j < TOPK; ++j) {
            const bool take0 = (c0 >= c1);            // tie -> smaller expert index
            float v  = take0 ? c0 : c1;
            float rr = take0 ? s0 : s1;
            int   ii = take0 ? lane : lane + 64;
#pragma unroll
            for (int off = 32; off > 0; off >>= 1) {  // lexicographic argmax
                const float ov  = __shfl_xor(v, off, 64);
                const float orr = __shfl_xor(rr, off, 64);
                const int   oi  = __shfl_xor(ii, off, 64);
                if (ov > v || (ov == v && oi < ii)) { v = ov; rr = orr; ii = oi; }
            }
            sel_i[j] = ii;
            sel_r[j] = rr;
            rsum += rr;
            if (ii == lane)      c0 = -__builtin_inff();
            if (ii == lane + 64) c1 = -__builtin_inff();
        }
        if (lane == 0) {
            const float inv = 1.0f / (rsum + 1e-20f);
            const size_t tok = (size_t)(row0 + t);
#pragma unroll
            for (int j = 0; j < TOPK; ++j) {
                out[tok * TOPK + j]                    = (float)sel_i[j];
                out[(size_t)T * TOPK + tok * TOPK + j] = sel_r[j] * inv;
            }
        }
    }
}

extern "C" void kernel_launch(void* const* d_in, const int* in_sizes, int n_in,
                              void* d_out, int out_size, void* d_ws, size_t ws_size,
                              hipStream_t stream) {
    const float* h    = (const float*)d_in[0];
    const float* w    = (const float*)d_in[1];
    const float* bias = (const float*)d_in[2];
    float* out = (float*)d_out;
    const int T = in_sizes[0] / HIDDEN;  // 16384

    float* wT2 = (float*)d_ws;           // 2 MB

    hipLaunchKernelGGL(transpose_w, dim3(NEXP * HIDDEN / 2 / 256), dim3(256), 0, stream, w, wT2);
    hipLaunchKernelGGL(router_kernel, dim3(T / BM), dim3(256), 0, stream,
                       h, wT2, bias, out, T);
}